// Round 1
// baseline (692.208 us; speedup 1.0000x reference)
//
#include <hip/hip_runtime.h>

typedef unsigned short ushort_t;
typedef unsigned int uint_t;
typedef __attribute__((ext_vector_type(8))) short s8v;     // 8 x bf16 (4 VGPRs)
typedef __attribute__((ext_vector_type(4))) float f4v;     // 4 x fp32 acc

// Problem constants (fixed by the reference)
#define NS0 100000
#define ND0 20000
#define ND1 4000
#define E0  640000
#define E1  128000
#define F   512     // IN_F == HID_F
#define OF  256

__device__ __forceinline__ ushort_t f2b(float f) {
    uint_t u = __float_as_uint(f);
    uint_t r = (u + 0x7fffu + ((u >> 16) & 1u)) >> 16;
    return (ushort_t)r;
}
__device__ __forceinline__ float b2f_lo(uint_t u) { return __uint_as_float(u << 16); }
__device__ __forceinline__ float b2f_hi(uint_t u) { return __uint_as_float(u & 0xffff0000u); }

// ---- degree counting: cnt layout [out0(100000) | in0(20000) | out1(20000) | in1(4000)]
__global__ __launch_bounds__(256) void count_deg(const int* __restrict__ src0, const int* __restrict__ dst0,
                                                 const int* __restrict__ src1, const int* __restrict__ dst1,
                                                 int* __restrict__ cnt) {
    int i = blockIdx.x * 256 + threadIdx.x;
    int stride = gridDim.x * 256;
    for (int e = i; e < E0; e += stride) {
        atomicAdd(&cnt[src0[e]], 1);
        atomicAdd(&cnt[NS0 + dst0[e]], 1);
    }
    for (int e = i; e < E1; e += stride) {
        atomicAdd(&cnt[NS0 + ND0 + src1[e]], 1);
        atomicAdd(&cnt[NS0 + ND0 + ND0 + dst1[e]], 1);
    }
}

__global__ __launch_bounds__(256) void rsq_kernel(const int* __restrict__ cnt, float* __restrict__ rsq, int n) {
    int i = blockIdx.x * 256 + threadIdx.x;
    if (i < n) rsq[i] = rsqrtf(fmaxf((float)cnt[i], 1.0f));
}

// single-block exclusive scan; also initializes cursor = offset
__global__ __launch_bounds__(1024) void scan_excl(const int* __restrict__ cnt, int n,
                                                  int* __restrict__ off, int* __restrict__ cur) {
    __shared__ int s[1024];
    __shared__ int carry;
    int lid = threadIdx.x;
    if (lid == 0) carry = 0;
    __syncthreads();
    for (int base = 0; base < n; base += 1024) {
        int i = base + lid;
        int v = (i < n) ? cnt[i] : 0;
        s[lid] = v;
        __syncthreads();
        #pragma unroll
        for (int d = 1; d < 1024; d <<= 1) {
            int t = (lid >= d) ? s[lid - d] : 0;
            __syncthreads();
            s[lid] += t;
            __syncthreads();
        }
        int excl = carry + s[lid] - v;
        if (i < n) { off[i] = excl; cur[i] = excl; }
        __syncthreads();
        if (lid == 1023) carry += s[1023];
        __syncthreads();
    }
}

__global__ __launch_bounds__(256) void fill_edges(const int* __restrict__ src0, const int* __restrict__ dst0,
                                                  const int* __restrict__ src1, const int* __restrict__ dst1,
                                                  int* __restrict__ cur0, int* __restrict__ cur1,
                                                  int* __restrict__ es0, int* __restrict__ es1) {
    int i = blockIdx.x * 256 + threadIdx.x;
    int stride = gridDim.x * 256;
    for (int e = i; e < E0; e += stride) {
        int d = dst0[e];
        int p = atomicAdd(&cur0[d], 1);
        es0[p] = src0[e];
    }
    for (int e = i; e < E1; e += stride) {
        int d = dst1[e];
        int p = atomicAdd(&cur1[d], 1);
        es1[p] = src1[e];
    }
}

// W1 [512,512] -> wt1 [N=512][K=512] bf16 ; W2 [512,256] -> wt2 [N=256][K=512] bf16
__global__ __launch_bounds__(256) void conv_w(const float* __restrict__ W1, const float* __restrict__ W2,
                                              ushort_t* __restrict__ wt1, ushort_t* __restrict__ wt2) {
    int i = blockIdx.x * 256 + threadIdx.x;
    if (i < F * F) {
        int k = i >> 9, n = i & (F - 1);
        wt1[n * F + k] = f2b(W1[i]);
    } else if (i < F * F + F * OF) {
        int j = i - F * F;
        int k = j >> 8, n = j & (OF - 1);
        wt2[n * F + k] = f2b(W2[j]);
    }
}

// x [NS0,512] fp32 -> xb bf16 pre-scaled by rsq_out0[row]
__global__ __launch_bounds__(256) void conv_x(const float* __restrict__ x, const float* __restrict__ rsq_out0,
                                              ushort_t* __restrict__ xb) {
    int i = blockIdx.x * 256 + threadIdx.x;   // pair index; 256 pairs per row
    if (i >= NS0 * 256) return;
    int row = i >> 8;
    float2 v = ((const float2*)x)[i];
    float sc = rsq_out0[row];
    uint_t lo = f2b(v.x * sc), hi = f2b(v.y * sc);
    ((uint_t*)xb)[i] = lo | (hi << 16);
}

// per-dst-row reduce over CSR edge list; X rows already pre-scaled bf16; write bf16 * rsq_in[d]
__global__ __launch_bounds__(256) void agg_bf16(const ushort_t* __restrict__ X, const int* __restrict__ es,
                                                const int* __restrict__ off, const int* __restrict__ cnt,
                                                const float* __restrict__ rsq_in, ushort_t* __restrict__ out) {
    int d = blockIdx.x;
    int t = threadIdx.x;            // 0..255, handles cols 2t, 2t+1
    int base = off[d], n = cnt[d];
    float ax = 0.f, ay = 0.f;
    for (int i = 0; i < n; ++i) {
        int s = es[base + i];
        uint_t u = ((const uint_t*)X)[(size_t)s * 256 + t];
        ax += b2f_lo(u);
        ay += b2f_hi(u);
    }
    float sc = rsq_in[d];
    ax *= sc; ay *= sc;
    ((uint_t*)out)[(size_t)d * 256 + t] = (uint_t)f2b(ax) | ((uint_t)f2b(ay) << 16);
}

// fallback when ws too small for xb: gather fp32 x, scale by rsq_out0[src]
__global__ __launch_bounds__(256) void agg_f32(const float* __restrict__ X, const float* __restrict__ rsq_out,
                                               const int* __restrict__ es, const int* __restrict__ off,
                                               const int* __restrict__ cnt, const float* __restrict__ rsq_in,
                                               ushort_t* __restrict__ out) {
    int d = blockIdx.x;
    int t = threadIdx.x;
    int base = off[d], n = cnt[d];
    float ax = 0.f, ay = 0.f;
    for (int i = 0; i < n; ++i) {
        int s = es[base + i];
        float2 v = ((const float2*)X)[(size_t)s * 256 + t];
        float sc = rsq_out[s];
        ax += v.x * sc;
        ay += v.y * sc;
    }
    float sc = rsq_in[d];
    ax *= sc; ay *= sc;
    ((uint_t*)out)[(size_t)d * 256 + t] = (uint_t)f2b(ax) | ((uint_t)f2b(ay) << 16);
}

// C[M,N] = relu(A[M,K]bf16 @ B + bias) (* rowScale), B given transposed BT[N,K] bf16.
// 64x64 tile per 256-thread block; wave w owns cols w*16..w*16+15, 4 m-tiles of 16.
template <typename OutT>
__global__ __launch_bounds__(256) void gemm_bias_relu(const ushort_t* __restrict__ A, const ushort_t* __restrict__ BT,
                                                      const float* __restrict__ bias, const float* __restrict__ rowScale,
                                                      OutT* __restrict__ C, int M, int N, int K) {
    __shared__ __align__(16) ushort_t As[64 * 72];
    __shared__ __align__(16) ushort_t Bs[64 * 72];
    int tid = threadIdx.x;
    int lane = tid & 63;
    int w = tid >> 6;
    int m16 = lane & 15, quad = lane >> 4;
    int r = tid >> 2;              // 0..63
    int cseg = (tid & 3) * 8;      // 0,8,16,24
    int rowA = blockIdx.x * 64 + r; if (rowA >= M) rowA = M - 1;
    int rowB = blockIdx.y * 64 + r;
    f4v acc[4] = {};
    for (int k0 = 0; k0 < K; k0 += 64) {
        *(uint4*)&As[r * 72 + cseg]      = *(const uint4*)(A + (size_t)rowA * K + k0 + cseg);
        *(uint4*)&As[r * 72 + cseg + 32] = *(const uint4*)(A + (size_t)rowA * K + k0 + cseg + 32);
        *(uint4*)&Bs[r * 72 + cseg]      = *(const uint4*)(BT + (size_t)rowB * K + k0 + cseg);
        *(uint4*)&Bs[r * 72 + cseg + 32] = *(const uint4*)(BT + (size_t)rowB * K + k0 + cseg + 32);
        __syncthreads();
        #pragma unroll
        for (int kc = 0; kc < 2; ++kc) {
            const int co = kc * 32 + quad * 8;
            s8v bf = *(const s8v*)&Bs[(w * 16 + m16) * 72 + co];
            s8v a0 = *(const s8v*)&As[(m16) * 72 + co];
            s8v a1 = *(const s8v*)&As[(16 + m16) * 72 + co];
            s8v a2 = *(const s8v*)&As[(32 + m16) * 72 + co];
            s8v a3 = *(const s8v*)&As[(48 + m16) * 72 + co];
            acc[0] = __builtin_amdgcn_mfma_f32_16x16x32_bf16(a0, bf, acc[0], 0, 0, 0);
            acc[1] = __builtin_amdgcn_mfma_f32_16x16x32_bf16(a1, bf, acc[1], 0, 0, 0);
            acc[2] = __builtin_amdgcn_mfma_f32_16x16x32_bf16(a2, bf, acc[2], 0, 0, 0);
            acc[3] = __builtin_amdgcn_mfma_f32_16x16x32_bf16(a3, bf, acc[3], 0, 0, 0);
        }
        __syncthreads();
    }
    int col = blockIdx.y * 64 + w * 16 + m16;
    float b = bias[col];
    #pragma unroll
    for (int mt = 0; mt < 4; ++mt) {
        #pragma unroll
        for (int rr = 0; rr < 4; ++rr) {
            int row = blockIdx.x * 64 + mt * 16 + quad * 4 + rr;
            if (row < M) {
                float v = acc[mt][rr] + b;
                v = fmaxf(v, 0.0f);
                if (rowScale) v *= rowScale[row];
                if (sizeof(OutT) == 2)
                    ((ushort_t*)C)[(size_t)row * N + col] = f2b(v);
                else
                    ((float*)C)[(size_t)row * N + col] = v;
            }
        }
    }
}

extern "C" void kernel_launch(void* const* d_in, const int* in_sizes, int n_in,
                              void* d_out, int out_size, void* d_ws, size_t ws_size,
                              hipStream_t stream) {
    (void)in_sizes; (void)n_in; (void)out_size;
    const float* x    = (const float*)d_in[0];
    const int*   src0 = (const int*)d_in[1];
    const int*   dst0 = (const int*)d_in[2];
    const int*   src1 = (const int*)d_in[3];
    const int*   dst1 = (const int*)d_in[4];
    const float* W1   = (const float*)d_in[5];
    const float* b1   = (const float*)d_in[6];
    const float* W2   = (const float*)d_in[7];
    const float* b2   = (const float*)d_in[8];
    float* out = (float*)d_out;

    char* p = (char*)d_ws;
    auto alloc = [&](size_t bytes) { char* q = p; p += (bytes + 255) & ~(size_t)255; return q; };
    const int NCNT = NS0 + ND0 + ND0 + ND1;      // 144000
    int*      cnt  = (int*)alloc((size_t)NCNT * 4);
    float*    rsq  = (float*)alloc((size_t)NCNT * 4);
    int*      off0 = (int*)alloc((size_t)ND0 * 4);
    int*      cur0 = (int*)alloc((size_t)ND0 * 4);
    int*      off1 = (int*)alloc((size_t)ND1 * 4);
    int*      cur1 = (int*)alloc((size_t)ND1 * 4);
    int*      es0  = (int*)alloc((size_t)E0 * 4);
    int*      es1  = (int*)alloc((size_t)E1 * 4);
    ushort_t* wt1  = (ushort_t*)alloc((size_t)F * F * 2);
    ushort_t* wt2  = (ushort_t*)alloc((size_t)OF * F * 2);
    ushort_t* agg0 = (ushort_t*)alloc((size_t)ND0 * F * 2);
    ushort_t* h    = (ushort_t*)alloc((size_t)ND0 * F * 2);
    ushort_t* agg1 = (ushort_t*)alloc((size_t)ND1 * F * 2);
    size_t used = (size_t)(p - (char*)d_ws);
    bool use_xb = (ws_size >= used + (size_t)NS0 * F * 2 + 512);
    ushort_t* xb = use_xb ? (ushort_t*)alloc((size_t)NS0 * F * 2) : nullptr;

    const float* rsq_out0 = rsq;
    const float* rsq_in0  = rsq + NS0;
    const float* rsq_out1 = rsq + NS0 + ND0;
    const float* rsq_in1  = rsq + NS0 + ND0 + ND0;

    hipMemsetAsync(cnt, 0, (size_t)NCNT * 4, stream);
    count_deg<<<E0 / 256, 256, 0, stream>>>(src0, dst0, src1, dst1, cnt);
    rsq_kernel<<<(NCNT + 255) / 256, 256, 0, stream>>>(cnt, rsq, NCNT);
    scan_excl<<<1, 1024, 0, stream>>>(cnt + NS0, ND0, off0, cur0);
    scan_excl<<<1, 1024, 0, stream>>>(cnt + NS0 + ND0 + ND0, ND1, off1, cur1);
    fill_edges<<<E0 / 256, 256, 0, stream>>>(src0, dst0, src1, dst1, cur0, cur1, es0, es1);
    conv_w<<<(F * F + F * OF) / 256, 256, 0, stream>>>(W1, W2, wt1, wt2);

    if (use_xb) {
        conv_x<<<(NS0 * 256) / 256, 256, 0, stream>>>(x, rsq_out0, xb);
        agg_bf16<<<ND0, 256, 0, stream>>>(xb, es0, off0, cnt + NS0, rsq_in0, agg0);
    } else {
        agg_f32<<<ND0, 256, 0, stream>>>(x, rsq_out0, es0, off0, cnt + NS0, rsq_in0, agg0);
    }

    gemm_bias_relu<ushort_t><<<dim3((ND0 + 63) / 64, F / 64), 256, 0, stream>>>(
        agg0, wt1, b1, rsq_out1, h, ND0, F, F);

    agg_bf16<<<ND1, 256, 0, stream>>>(h, es1, off1, cnt + NS0 + ND0 + ND0, rsq_in1, agg1);

    gemm_bias_relu<float><<<dim3((ND1 + 63) / 64, OF / 64), 256, 0, stream>>>(
        agg1, wt2, b2, nullptr, out, ND1, OF, F);
}

// Round 2
// 608.785 us; speedup vs baseline: 1.1370x; 1.1370x over previous
//
#include <hip/hip_runtime.h>

typedef unsigned short ushort_t;
typedef unsigned int uint_t;
typedef __attribute__((ext_vector_type(8))) short s8v;     // 8 x bf16 (4 VGPRs)
typedef __attribute__((ext_vector_type(4))) float f4v;     // 4 x fp32 acc

// Problem constants (fixed by the reference)
#define NS0 100000
#define ND0 20000
#define ND1 4000
#define E0  640000
#define E1  128000
#define F   512     // IN_F == HID_F
#define OF  256

__device__ __forceinline__ ushort_t f2b(float f) {
    uint_t u = __float_as_uint(f);
    uint_t r = (u + 0x7fffu + ((u >> 16) & 1u)) >> 16;
    return (ushort_t)r;
}
__device__ __forceinline__ float b2f_lo(uint_t u) { return __uint_as_float(u << 16); }
__device__ __forceinline__ float b2f_hi(uint_t u) { return __uint_as_float(u & 0xffff0000u); }

// ---- degree counting: cnt layout [out0(100000) | in0(20000) | out1(20000) | in1(4000)]
__global__ __launch_bounds__(256) void count_deg(const int* __restrict__ src0, const int* __restrict__ dst0,
                                                 const int* __restrict__ src1, const int* __restrict__ dst1,
                                                 int* __restrict__ cnt) {
    int i = blockIdx.x * 256 + threadIdx.x;
    int stride = gridDim.x * 256;
    for (int e = i; e < E0; e += stride) {
        atomicAdd(&cnt[src0[e]], 1);
        atomicAdd(&cnt[NS0 + dst0[e]], 1);
    }
    for (int e = i; e < E1; e += stride) {
        atomicAdd(&cnt[NS0 + ND0 + src1[e]], 1);
        atomicAdd(&cnt[NS0 + ND0 + ND0 + dst1[e]], 1);
    }
}

__global__ __launch_bounds__(256) void rsq_kernel(const int* __restrict__ cnt, float* __restrict__ rsq, int n) {
    int i = blockIdx.x * 256 + threadIdx.x;
    if (i < n) rsq[i] = rsqrtf(fmaxf((float)cnt[i], 1.0f));
}

// single-block exclusive scan, shuffle-based (3 barriers/tile); also inits cursor = offset
__global__ __launch_bounds__(1024) void scan_excl(const int* __restrict__ cnt, int n,
                                                  int* __restrict__ off, int* __restrict__ cur) {
    __shared__ int wsum[16];
    __shared__ int wexc[16];
    __shared__ int tsum;
    __shared__ int carry;
    int lid = threadIdx.x;
    int lane = lid & 63;
    int w = lid >> 6;
    if (lid == 0) carry = 0;
    __syncthreads();
    for (int base = 0; base < n; base += 1024) {
        int i = base + lid;
        int v = (i < n) ? cnt[i] : 0;
        // inclusive wave scan
        int s = v;
        #pragma unroll
        for (int d = 1; d < 64; d <<= 1) {
            int t = __shfl_up(s, d, 64);
            if (lane >= d) s += t;
        }
        if (lane == 63) wsum[w] = s;
        __syncthreads();
        if (w == 0 && lane < 16) {
            int ws = wsum[lane];
            int ss = ws;
            #pragma unroll
            for (int d = 1; d < 16; d <<= 1) {
                int t = __shfl_up(ss, d, 64);
                if (lane >= d) ss += t;
            }
            wexc[lane] = ss - ws;
            if (lane == 15) tsum = ss;
        }
        __syncthreads();
        int excl = carry + wexc[w] + s - v;
        if (i < n) { off[i] = excl; cur[i] = excl; }
        __syncthreads();
        if (lid == 0) carry += tsum;
        __syncthreads();
    }
}

__global__ __launch_bounds__(256) void fill_edges(const int* __restrict__ src0, const int* __restrict__ dst0,
                                                  const int* __restrict__ src1, const int* __restrict__ dst1,
                                                  int* __restrict__ cur0, int* __restrict__ cur1,
                                                  int* __restrict__ es0, int* __restrict__ es1) {
    int i = blockIdx.x * 256 + threadIdx.x;
    int stride = gridDim.x * 256;
    for (int e = i; e < E0; e += stride) {
        int d = dst0[e];
        int p = atomicAdd(&cur0[d], 1);
        es0[p] = src0[e];
    }
    for (int e = i; e < E1; e += stride) {
        int d = dst1[e];
        int p = atomicAdd(&cur1[d], 1);
        es1[p] = src1[e];
    }
}

// W1 [512,512] -> wt1 [N=512][K=512] bf16 ; W2 [512,256] -> wt2 [N=256][K=512] bf16
__global__ __launch_bounds__(256) void conv_w(const float* __restrict__ W1, const float* __restrict__ W2,
                                              ushort_t* __restrict__ wt1, ushort_t* __restrict__ wt2) {
    int i = blockIdx.x * 256 + threadIdx.x;
    if (i < F * F) {
        int k = i >> 9, n = i & (F - 1);
        wt1[n * F + k] = f2b(W1[i]);
    } else if (i < F * F + F * OF) {
        int j = i - F * F;
        int k = j >> 8, n = j & (OF - 1);
        wt2[n * F + k] = f2b(W2[j]);
    }
}

// x [NS0,512] fp32 -> xb bf16 pre-scaled by rsq_out0[row]; float4 reads, uint2 writes
__global__ __launch_bounds__(256) void conv_x(const float* __restrict__ x, const float* __restrict__ rsq_out0,
                                              ushort_t* __restrict__ xb) {
    int i = blockIdx.x * 256 + threadIdx.x;   // quad index; 128 quads per row
    if (i >= NS0 * 128) return;
    int row = i >> 7;
    float4 v = ((const float4*)x)[i];
    float sc = rsq_out0[row];
    uint2 o;
    o.x = (uint_t)f2b(v.x * sc) | ((uint_t)f2b(v.y * sc) << 16);
    o.y = (uint_t)f2b(v.z * sc) | ((uint_t)f2b(v.w * sc) << 16);
    ((uint2*)xb)[i] = o;
}

__device__ __forceinline__ void add8(float* acc, uint4 u) {
    acc[0] += b2f_lo(u.x); acc[1] += b2f_hi(u.x);
    acc[2] += b2f_lo(u.y); acc[3] += b2f_hi(u.y);
    acc[4] += b2f_lo(u.z); acc[5] += b2f_hi(u.z);
    acc[6] += b2f_lo(u.w); acc[7] += b2f_hi(u.w);
}

// One wave per dst row. 64 lanes x 16B = full 1024B row per load instruction.
// Edge loop unrolled x4 -> 4 independent loads in flight per wave (16/block).
__global__ __launch_bounds__(256) void agg_bf16(const ushort_t* __restrict__ X, const int* __restrict__ es,
                                                const int* __restrict__ off, const int* __restrict__ cnt,
                                                const float* __restrict__ rsq_in, ushort_t* __restrict__ out,
                                                int ndst) {
    int d = __builtin_amdgcn_readfirstlane(blockIdx.x * 4 + (threadIdx.x >> 6));
    if (d >= ndst) return;
    int lane = threadIdx.x & 63;
    int base = off[d], n = cnt[d];
    const uint4* Xv = (const uint4*)X;
    float acc[8] = {0.f, 0.f, 0.f, 0.f, 0.f, 0.f, 0.f, 0.f};
    int i = 0;
    for (; i + 4 <= n; i += 4) {
        int s0 = es[base + i];
        int s1 = es[base + i + 1];
        int s2 = es[base + i + 2];
        int s3 = es[base + i + 3];
        uint4 u0 = Xv[(size_t)s0 * 64 + lane];
        uint4 u1 = Xv[(size_t)s1 * 64 + lane];
        uint4 u2 = Xv[(size_t)s2 * 64 + lane];
        uint4 u3 = Xv[(size_t)s3 * 64 + lane];
        add8(acc, u0); add8(acc, u1); add8(acc, u2); add8(acc, u3);
    }
    for (; i < n; ++i) {
        int s = es[base + i];
        uint4 u = Xv[(size_t)s * 64 + lane];
        add8(acc, u);
    }
    float sc = rsq_in[d];
    uint4 o;
    o.x = (uint_t)f2b(acc[0] * sc) | ((uint_t)f2b(acc[1] * sc) << 16);
    o.y = (uint_t)f2b(acc[2] * sc) | ((uint_t)f2b(acc[3] * sc) << 16);
    o.z = (uint_t)f2b(acc[4] * sc) | ((uint_t)f2b(acc[5] * sc) << 16);
    o.w = (uint_t)f2b(acc[6] * sc) | ((uint_t)f2b(acc[7] * sc) << 16);
    ((uint4*)out)[(size_t)d * 64 + lane] = o;
}

// fallback when ws too small for xb: gather fp32 x, scale by rsq_out0[src]
__global__ __launch_bounds__(256) void agg_f32(const float* __restrict__ X, const float* __restrict__ rsq_out,
                                               const int* __restrict__ es, const int* __restrict__ off,
                                               const int* __restrict__ cnt, const float* __restrict__ rsq_in,
                                               ushort_t* __restrict__ out) {
    int d = blockIdx.x;
    int t = threadIdx.x;
    int base = off[d], n = cnt[d];
    float ax = 0.f, ay = 0.f;
    for (int i = 0; i < n; ++i) {
        int s = es[base + i];
        float2 v = ((const float2*)X)[(size_t)s * 256 + t];
        float sc = rsq_out[s];
        ax += v.x * sc;
        ay += v.y * sc;
    }
    float sc = rsq_in[d];
    ax *= sc; ay *= sc;
    ((uint_t*)out)[(size_t)d * 256 + t] = (uint_t)f2b(ax) | ((uint_t)f2b(ay) << 16);
}

// C[M,N] = relu(A[M,K]bf16 @ B + bias) (* rowScale), B given transposed BT[N,K] bf16.
// 64x64 tile per 256-thread block; wave w owns cols w*16..w*16+15, 4 m-tiles of 16.
template <typename OutT>
__global__ __launch_bounds__(256) void gemm_bias_relu(const ushort_t* __restrict__ A, const ushort_t* __restrict__ BT,
                                                      const float* __restrict__ bias, const float* __restrict__ rowScale,
                                                      OutT* __restrict__ C, int M, int N, int K) {
    __shared__ __align__(16) ushort_t As[64 * 72];
    __shared__ __align__(16) ushort_t Bs[64 * 72];
    int tid = threadIdx.x;
    int lane = tid & 63;
    int w = tid >> 6;
    int m16 = lane & 15, quad = lane >> 4;
    int r = tid >> 2;              // 0..63
    int cseg = (tid & 3) * 8;      // 0,8,16,24
    int rowA = blockIdx.x * 64 + r; if (rowA >= M) rowA = M - 1;
    int rowB = blockIdx.y * 64 + r;
    f4v acc[4] = {};
    for (int k0 = 0; k0 < K; k0 += 64) {
        *(uint4*)&As[r * 72 + cseg]      = *(const uint4*)(A + (size_t)rowA * K + k0 + cseg);
        *(uint4*)&As[r * 72 + cseg + 32] = *(const uint4*)(A + (size_t)rowA * K + k0 + cseg + 32);
        *(uint4*)&Bs[r * 72 + cseg]      = *(const uint4*)(BT + (size_t)rowB * K + k0 + cseg);
        *(uint4*)&Bs[r * 72 + cseg + 32] = *(const uint4*)(BT + (size_t)rowB * K + k0 + cseg + 32);
        __syncthreads();
        #pragma unroll
        for (int kc = 0; kc < 2; ++kc) {
            const int co = kc * 32 + quad * 8;
            s8v bf = *(const s8v*)&Bs[(w * 16 + m16) * 72 + co];
            s8v a0 = *(const s8v*)&As[(m16) * 72 + co];
            s8v a1 = *(const s8v*)&As[(16 + m16) * 72 + co];
            s8v a2 = *(const s8v*)&As[(32 + m16) * 72 + co];
            s8v a3 = *(const s8v*)&As[(48 + m16) * 72 + co];
            acc[0] = __builtin_amdgcn_mfma_f32_16x16x32_bf16(a0, bf, acc[0], 0, 0, 0);
            acc[1] = __builtin_amdgcn_mfma_f32_16x16x32_bf16(a1, bf, acc[1], 0, 0, 0);
            acc[2] = __builtin_amdgcn_mfma_f32_16x16x32_bf16(a2, bf, acc[2], 0, 0, 0);
            acc[3] = __builtin_amdgcn_mfma_f32_16x16x32_bf16(a3, bf, acc[3], 0, 0, 0);
        }
        __syncthreads();
    }
    int col = blockIdx.y * 64 + w * 16 + m16;
    float b = bias[col];
    #pragma unroll
    for (int mt = 0; mt < 4; ++mt) {
        #pragma unroll
        for (int rr = 0; rr < 4; ++rr) {
            int row = blockIdx.x * 64 + mt * 16 + quad * 4 + rr;
            if (row < M) {
                float v = acc[mt][rr] + b;
                v = fmaxf(v, 0.0f);
                if (rowScale) v *= rowScale[row];
                if (sizeof(OutT) == 2)
                    ((ushort_t*)C)[(size_t)row * N + col] = f2b(v);
                else
                    ((float*)C)[(size_t)row * N + col] = v;
            }
        }
    }
}

extern "C" void kernel_launch(void* const* d_in, const int* in_sizes, int n_in,
                              void* d_out, int out_size, void* d_ws, size_t ws_size,
                              hipStream_t stream) {
    (void)in_sizes; (void)n_in; (void)out_size;
    const float* x    = (const float*)d_in[0];
    const int*   src0 = (const int*)d_in[1];
    const int*   dst0 = (const int*)d_in[2];
    const int*   src1 = (const int*)d_in[3];
    const int*   dst1 = (const int*)d_in[4];
    const float* W1   = (const float*)d_in[5];
    const float* b1   = (const float*)d_in[6];
    const float* W2   = (const float*)d_in[7];
    const float* b2   = (const float*)d_in[8];
    float* out = (float*)d_out;

    char* p = (char*)d_ws;
    auto alloc = [&](size_t bytes) { char* q = p; p += (bytes + 255) & ~(size_t)255; return q; };
    const int NCNT = NS0 + ND0 + ND0 + ND1;      // 144000
    int*      cnt  = (int*)alloc((size_t)NCNT * 4);
    float*    rsq  = (float*)alloc((size_t)NCNT * 4);
    int*      off0 = (int*)alloc((size_t)ND0 * 4);
    int*      cur0 = (int*)alloc((size_t)ND0 * 4);
    int*      off1 = (int*)alloc((size_t)ND1 * 4);
    int*      cur1 = (int*)alloc((size_t)ND1 * 4);
    int*      es0  = (int*)alloc((size_t)E0 * 4);
    int*      es1  = (int*)alloc((size_t)E1 * 4);
    ushort_t* wt1  = (ushort_t*)alloc((size_t)F * F * 2);
    ushort_t* wt2  = (ushort_t*)alloc((size_t)OF * F * 2);
    ushort_t* agg0 = (ushort_t*)alloc((size_t)ND0 * F * 2);
    ushort_t* h    = (ushort_t*)alloc((size_t)ND0 * F * 2);
    ushort_t* agg1 = (ushort_t*)alloc((size_t)ND1 * F * 2);
    size_t used = (size_t)(p - (char*)d_ws);
    bool use_xb = (ws_size >= used + (size_t)NS0 * F * 2 + 512);
    ushort_t* xb = use_xb ? (ushort_t*)alloc((size_t)NS0 * F * 2) : nullptr;

    const float* rsq_out0 = rsq;
    const float* rsq_in0  = rsq + NS0;
    const float* rsq_out1 = rsq + NS0 + ND0;
    const float* rsq_in1  = rsq + NS0 + ND0 + ND0;

    hipMemsetAsync(cnt, 0, (size_t)NCNT * 4, stream);
    count_deg<<<E0 / 256, 256, 0, stream>>>(src0, dst0, src1, dst1, cnt);
    rsq_kernel<<<(NCNT + 255) / 256, 256, 0, stream>>>(cnt, rsq, NCNT);
    scan_excl<<<1, 1024, 0, stream>>>(cnt + NS0, ND0, off0, cur0);
    scan_excl<<<1, 1024, 0, stream>>>(cnt + NS0 + ND0 + ND0, ND1, off1, cur1);
    fill_edges<<<E0 / 256, 256, 0, stream>>>(src0, dst0, src1, dst1, cur0, cur1, es0, es1);
    conv_w<<<(F * F + F * OF) / 256, 256, 0, stream>>>(W1, W2, wt1, wt2);

    if (use_xb) {
        conv_x<<<(NS0 * 128 + 255) / 256, 256, 0, stream>>>(x, rsq_out0, xb);
        agg_bf16<<<(ND0 + 3) / 4, 256, 0, stream>>>(xb, es0, off0, cnt + NS0, rsq_in0, agg0, ND0);
    } else {
        agg_f32<<<ND0, 256, 0, stream>>>(x, rsq_out0, es0, off0, cnt + NS0, rsq_in0, agg0);
    }

    gemm_bias_relu<ushort_t><<<dim3((ND0 + 63) / 64, F / 64), 256, 0, stream>>>(
        agg0, wt1, b1, rsq_out1, h, ND0, F, F);

    agg_bf16<<<(ND1 + 3) / 4, 256, 0, stream>>>(h, es1, off1, cnt + NS0 + ND0 + ND0, rsq_in1, agg1, ND1);

    gemm_bias_relu<float><<<dim3((ND1 + 63) / 64, OF / 64), 256, 0, stream>>>(
        agg1, wt2, b2, nullptr, out, ND1, OF, F);
}

// Round 3
// 608.192 us; speedup vs baseline: 1.1381x; 1.0010x over previous
//
#include <hip/hip_runtime.h>

typedef unsigned short ushort_t;
typedef unsigned int uint_t;
typedef __attribute__((ext_vector_type(8))) short s8v;     // 8 x bf16 (4 VGPRs)
typedef __attribute__((ext_vector_type(4))) float f4v;     // 4 x fp32 acc

// Problem constants (fixed by the reference)
#define NS0 100000
#define ND0 20000
#define ND1 4000
#define E0  640000
#define E1  128000
#define F   512     // IN_F == HID_F
#define OF  256

__device__ __forceinline__ ushort_t f2b(float f) {
    uint_t u = __float_as_uint(f);
    uint_t r = (u + 0x7fffu + ((u >> 16) & 1u)) >> 16;
    return (ushort_t)r;
}
__device__ __forceinline__ float b2f_lo(uint_t u) { return __uint_as_float(u << 16); }
__device__ __forceinline__ float b2f_hi(uint_t u) { return __uint_as_float(u & 0xffff0000u); }

// ---- degree counting: cnt layout [out0(100000) | in0(20000) | out1(20000) | in1(4000)]
__global__ __launch_bounds__(256) void count_deg(const int* __restrict__ src0, const int* __restrict__ dst0,
                                                 const int* __restrict__ src1, const int* __restrict__ dst1,
                                                 int* __restrict__ cnt) {
    int i = blockIdx.x * 256 + threadIdx.x;
    int stride = gridDim.x * 256;
    for (int e = i; e < E0; e += stride) {
        atomicAdd(&cnt[src0[e]], 1);
        atomicAdd(&cnt[NS0 + dst0[e]], 1);
    }
    for (int e = i; e < E1; e += stride) {
        atomicAdd(&cnt[NS0 + ND0 + src1[e]], 1);
        atomicAdd(&cnt[NS0 + ND0 + ND0 + dst1[e]], 1);
    }
}

__global__ __launch_bounds__(256) void rsq_kernel(const int* __restrict__ cnt, float* __restrict__ rsq, int n) {
    int i = blockIdx.x * 256 + threadIdx.x;
    if (i < n) rsq[i] = rsqrtf(fmaxf((float)cnt[i], 1.0f));
}

// Chunked exclusive scan: thread t serially owns elements [t*ch, t*ch+ch).
// 2 barriers total per block. Block 0 scans level-0 (n0), block 1 scans level-1 (n1).
__global__ __launch_bounds__(1024) void scan_both(const int* __restrict__ cnt0, int n0,
                                                  int* __restrict__ off0, int* __restrict__ cur0,
                                                  const int* __restrict__ cnt1, int n1,
                                                  int* __restrict__ off1, int* __restrict__ cur1) {
    const int* cnt = blockIdx.x ? cnt1 : cnt0;
    int n = blockIdx.x ? n1 : n0;
    int* off = blockIdx.x ? off1 : off0;
    int* cur = blockIdx.x ? cur1 : cur0;
    __shared__ int wsum[16];
    __shared__ int wexc[16];
    int lid = threadIdx.x, lane = lid & 63, w = lid >> 6;
    int ch = (n + 1023) >> 10;
    int s0 = lid * ch;
    int e0 = min(s0 + ch, n);
    int sum = 0;
    for (int i = s0; i < e0; ++i) sum += cnt[i];
    int s = sum;
    #pragma unroll
    for (int d = 1; d < 64; d <<= 1) { int t = __shfl_up(s, d, 64); if (lane >= d) s += t; }
    if (lane == 63) wsum[w] = s;
    __syncthreads();
    if (w == 0 && lane < 16) {
        int ws = wsum[lane];
        int ss = ws;
        #pragma unroll
        for (int d = 1; d < 16; d <<= 1) { int t = __shfl_up(ss, d, 64); if (lane >= d) ss += t; }
        wexc[lane] = ss - ws;
    }
    __syncthreads();
    int run = wexc[w] + s - sum;   // global exclusive prefix at s0
    for (int i = s0; i < e0; ++i) {
        int v = cnt[i];
        off[i] = run; cur[i] = run;
        run += v;
    }
}

__global__ __launch_bounds__(256) void fill_edges(const int* __restrict__ src0, const int* __restrict__ dst0,
                                                  const int* __restrict__ src1, const int* __restrict__ dst1,
                                                  int* __restrict__ cur0, int* __restrict__ cur1,
                                                  int* __restrict__ es0, int* __restrict__ es1) {
    int i = blockIdx.x * 256 + threadIdx.x;
    int stride = gridDim.x * 256;
    for (int e = i; e < E0; e += stride) {
        int d = dst0[e];
        int p = atomicAdd(&cur0[d], 1);
        es0[p] = src0[e];
    }
    for (int e = i; e < E1; e += stride) {
        int d = dst1[e];
        int p = atomicAdd(&cur1[d], 1);
        es1[p] = src1[e];
    }
}

// W1 [512,512] -> wt1 [N=512][K=512] bf16 ; W2 [512,256] -> wt2 [N=256][K=512] bf16
__global__ __launch_bounds__(256) void conv_w(const float* __restrict__ W1, const float* __restrict__ W2,
                                              ushort_t* __restrict__ wt1, ushort_t* __restrict__ wt2) {
    int i = blockIdx.x * 256 + threadIdx.x;
    if (i < F * F) {
        int k = i >> 9, n = i & (F - 1);
        wt1[n * F + k] = f2b(W1[i]);
    } else if (i < F * F + F * OF) {
        int j = i - F * F;
        int k = j >> 8, n = j & (OF - 1);
        wt2[n * F + k] = f2b(W2[j]);
    }
}

// x [NS0,512] fp32 -> xb bf16 pre-scaled by rsq_out0[row]; float4 reads, uint2 writes
__global__ __launch_bounds__(256) void conv_x(const float* __restrict__ x, const float* __restrict__ rsq_out0,
                                              ushort_t* __restrict__ xb) {
    int i = blockIdx.x * 256 + threadIdx.x;   // quad index; 128 quads per row
    if (i >= NS0 * 128) return;
    int row = i >> 7;
    float4 v = ((const float4*)x)[i];
    float sc = rsq_out0[row];
    uint2 o;
    o.x = (uint_t)f2b(v.x * sc) | ((uint_t)f2b(v.y * sc) << 16);
    o.y = (uint_t)f2b(v.z * sc) | ((uint_t)f2b(v.w * sc) << 16);
    ((uint2*)xb)[i] = o;
}

__device__ __forceinline__ void add8(float* acc, uint4 u) {
    acc[0] += b2f_lo(u.x); acc[1] += b2f_hi(u.x);
    acc[2] += b2f_lo(u.y); acc[3] += b2f_hi(u.y);
    acc[4] += b2f_lo(u.z); acc[5] += b2f_hi(u.z);
    acc[6] += b2f_lo(u.w); acc[7] += b2f_hi(u.w);
}

// One wave per dst row. 64 lanes x 16B = full 1024B row per load instruction.
// Edge loop unrolled x8 -> 8 independent loads in flight per wave.
__global__ __launch_bounds__(256) void agg_bf16(const ushort_t* __restrict__ X, const int* __restrict__ es,
                                                const int* __restrict__ off, const int* __restrict__ cnt,
                                                const float* __restrict__ rsq_in, ushort_t* __restrict__ out,
                                                int ndst) {
    int d = __builtin_amdgcn_readfirstlane(blockIdx.x * 4 + (threadIdx.x >> 6));
    if (d >= ndst) return;
    int lane = threadIdx.x & 63;
    int base = off[d], n = cnt[d];
    const uint4* Xv = (const uint4*)X;
    float acc[8] = {0.f, 0.f, 0.f, 0.f, 0.f, 0.f, 0.f, 0.f};
    int i = 0;
    for (; i + 8 <= n; i += 8) {
        uint4 u[8];
        #pragma unroll
        for (int j = 0; j < 8; ++j) u[j] = Xv[(size_t)es[base + i + j] * 64 + lane];
        #pragma unroll
        for (int j = 0; j < 8; ++j) add8(acc, u[j]);
    }
    for (; i + 2 <= n; i += 2) {
        uint4 u0 = Xv[(size_t)es[base + i] * 64 + lane];
        uint4 u1 = Xv[(size_t)es[base + i + 1] * 64 + lane];
        add8(acc, u0); add8(acc, u1);
    }
    if (i < n) add8(acc, Xv[(size_t)es[base + i] * 64 + lane]);
    float sc = rsq_in[d];
    uint4 o;
    o.x = (uint_t)f2b(acc[0] * sc) | ((uint_t)f2b(acc[1] * sc) << 16);
    o.y = (uint_t)f2b(acc[2] * sc) | ((uint_t)f2b(acc[3] * sc) << 16);
    o.z = (uint_t)f2b(acc[4] * sc) | ((uint_t)f2b(acc[5] * sc) << 16);
    o.w = (uint_t)f2b(acc[6] * sc) | ((uint_t)f2b(acc[7] * sc) << 16);
    ((uint4*)out)[(size_t)d * 64 + lane] = o;
}

// fallback when ws too small for xb: gather fp32 x, scale by rsq_out0[src]
__global__ __launch_bounds__(256) void agg_f32(const float* __restrict__ X, const float* __restrict__ rsq_out,
                                               const int* __restrict__ es, const int* __restrict__ off,
                                               const int* __restrict__ cnt, const float* __restrict__ rsq_in,
                                               ushort_t* __restrict__ out) {
    int d = blockIdx.x;
    int t = threadIdx.x;
    int base = off[d], n = cnt[d];
    float ax = 0.f, ay = 0.f;
    for (int i = 0; i < n; ++i) {
        int s = es[base + i];
        float2 v = ((const float2*)X)[(size_t)s * 256 + t];
        float sc = rsq_out[s];
        ax += v.x * sc;
        ay += v.y * sc;
    }
    float sc = rsq_in[d];
    ax *= sc; ay *= sc;
    ((uint_t*)out)[(size_t)d * 256 + t] = (uint_t)f2b(ax) | ((uint_t)f2b(ay) << 16);
}

// m97-style GEMM: C[M,N] = relu(A[M,K]bf16 @ BT[N,K]bf16^T + bias) (* rowScale)
// 128x128 tile / 256 threads / BK=64; global_load_lds 16B staging; 32 MFMA per K-step/wave.
template <typename OutT>
__global__ __launch_bounds__(256) void gemm128(const ushort_t* __restrict__ A, const ushort_t* __restrict__ BT,
                                               const float* __restrict__ bias, const float* __restrict__ rowScale,
                                               OutT* __restrict__ C, int M, int N, int K) {
    __shared__ __align__(16) ushort_t As[128 * 64];
    __shared__ __align__(16) ushort_t Bs[128 * 64];
    int tid = threadIdx.x;
    int lane = tid & 63, w = tid >> 6;
    int m16 = lane & 15, quad = lane >> 4;
    int wm = w & 1, wn = w >> 1;
    int bm = blockIdx.x * 128, bn = blockIdx.y * 128;
    f4v acc[4][4] = {};
    for (int k0 = 0; k0 < K; k0 += 64) {
        #pragma unroll
        for (int i = 0; i < 4; ++i) {
            int c = i * 256 + tid;          // chunk id: row = c>>3, 16B seg = c&7
            int row = c >> 3, seg = (c & 7) * 8;
            int ra = bm + row; if (ra >= M) ra = M - 1;
            __builtin_amdgcn_global_load_lds(
                (const __attribute__((address_space(1))) uint_t*)(A + (size_t)ra * K + k0 + seg),
                (__attribute__((address_space(3))) uint_t*)(As + (size_t)c * 8), 16, 0, 0);
        }
        #pragma unroll
        for (int i = 0; i < 4; ++i) {
            int c = i * 256 + tid;
            int row = c >> 3, seg = (c & 7) * 8;
            int rb = bn + row;              // N is a multiple of 128 here
            __builtin_amdgcn_global_load_lds(
                (const __attribute__((address_space(1))) uint_t*)(BT + (size_t)rb * K + k0 + seg),
                (__attribute__((address_space(3))) uint_t*)(Bs + (size_t)c * 8), 16, 0, 0);
        }
        __syncthreads();
        #pragma unroll
        for (int kc = 0; kc < 2; ++kc) {
            int co = kc * 32 + quad * 8;
            s8v af[4], bf[4];
            #pragma unroll
            for (int m = 0; m < 4; ++m)
                af[m] = *(const s8v*)&As[(wm * 64 + m * 16 + m16) * 64 + co];
            #pragma unroll
            for (int nn = 0; nn < 4; ++nn)
                bf[nn] = *(const s8v*)&Bs[(wn * 64 + nn * 16 + m16) * 64 + co];
            #pragma unroll
            for (int m = 0; m < 4; ++m)
                #pragma unroll
                for (int nn = 0; nn < 4; ++nn)
                    acc[m][nn] = __builtin_amdgcn_mfma_f32_16x16x32_bf16(af[m], bf[nn], acc[m][nn], 0, 0, 0);
        }
        __syncthreads();
    }
    #pragma unroll
    for (int m = 0; m < 4; ++m) {
        #pragma unroll
        for (int rr = 0; rr < 4; ++rr) {
            int row = bm + wm * 64 + m * 16 + quad * 4 + rr;
            if (row < M) {
                float rs = rowScale ? rowScale[row] : 1.0f;
                #pragma unroll
                for (int nn = 0; nn < 4; ++nn) {
                    int col = bn + wn * 64 + nn * 16 + m16;
                    float v = fmaxf(acc[m][nn][rr] + bias[col], 0.0f) * rs;
                    if (sizeof(OutT) == 2)
                        ((ushort_t*)C)[(size_t)row * N + col] = f2b(v);
                    else
                        ((float*)C)[(size_t)row * N + col] = v;
                }
            }
        }
    }
}

extern "C" void kernel_launch(void* const* d_in, const int* in_sizes, int n_in,
                              void* d_out, int out_size, void* d_ws, size_t ws_size,
                              hipStream_t stream) {
    (void)in_sizes; (void)n_in; (void)out_size;
    const float* x    = (const float*)d_in[0];
    const int*   src0 = (const int*)d_in[1];
    const int*   dst0 = (const int*)d_in[2];
    const int*   src1 = (const int*)d_in[3];
    const int*   dst1 = (const int*)d_in[4];
    const float* W1   = (const float*)d_in[5];
    const float* b1   = (const float*)d_in[6];
    const float* W2   = (const float*)d_in[7];
    const float* b2   = (const float*)d_in[8];
    float* out = (float*)d_out;

    char* p = (char*)d_ws;
    auto alloc = [&](size_t bytes) { char* q = p; p += (bytes + 255) & ~(size_t)255; return q; };
    const int NCNT = NS0 + ND0 + ND0 + ND1;      // 144000
    int*      cnt  = (int*)alloc((size_t)NCNT * 4);
    float*    rsq  = (float*)alloc((size_t)NCNT * 4);
    int*      off0 = (int*)alloc((size_t)ND0 * 4);
    int*      cur0 = (int*)alloc((size_t)ND0 * 4);
    int*      off1 = (int*)alloc((size_t)ND1 * 4);
    int*      cur1 = (int*)alloc((size_t)ND1 * 4);
    int*      es0  = (int*)alloc((size_t)E0 * 4);
    int*      es1  = (int*)alloc((size_t)E1 * 4);
    ushort_t* wt1  = (ushort_t*)alloc((size_t)F * F * 2);
    ushort_t* wt2  = (ushort_t*)alloc((size_t)OF * F * 2);
    ushort_t* agg0 = (ushort_t*)alloc((size_t)ND0 * F * 2);
    ushort_t* h    = (ushort_t*)alloc((size_t)ND0 * F * 2);
    ushort_t* agg1 = (ushort_t*)alloc((size_t)ND1 * F * 2);
    size_t used = (size_t)(p - (char*)d_ws);
    bool use_xb = (ws_size >= used + (size_t)NS0 * F * 2 + 512);
    ushort_t* xb = use_xb ? (ushort_t*)alloc((size_t)NS0 * F * 2) : nullptr;

    const float* rsq_out0 = rsq;
    const float* rsq_in0  = rsq + NS0;
    const float* rsq_out1 = rsq + NS0 + ND0;
    const float* rsq_in1  = rsq + NS0 + ND0 + ND0;

    hipMemsetAsync(cnt, 0, (size_t)NCNT * 4, stream);
    count_deg<<<E0 / 256, 256, 0, stream>>>(src0, dst0, src1, dst1, cnt);
    rsq_kernel<<<(NCNT + 255) / 256, 256, 0, stream>>>(cnt, rsq, NCNT);
    scan_both<<<2, 1024, 0, stream>>>(cnt + NS0, ND0, off0, cur0,
                                      cnt + NS0 + ND0 + ND0, ND1, off1, cur1);
    fill_edges<<<E0 / 256, 256, 0, stream>>>(src0, dst0, src1, dst1, cur0, cur1, es0, es1);
    conv_w<<<(F * F + F * OF) / 256, 256, 0, stream>>>(W1, W2, wt1, wt2);

    if (use_xb) {
        conv_x<<<(NS0 * 128 + 255) / 256, 256, 0, stream>>>(x, rsq_out0, xb);
        agg_bf16<<<(ND0 + 3) / 4, 256, 0, stream>>>(xb, es0, off0, cnt + NS0, rsq_in0, agg0, ND0);
    } else {
        agg_f32<<<ND0, 256, 0, stream>>>(x, rsq_out0, es0, off0, cnt + NS0, rsq_in0, agg0);
    }

    gemm128<ushort_t><<<dim3((ND0 + 127) / 128, F / 128), 256, 0, stream>>>(
        agg0, wt1, b1, rsq_out1, h, ND0, F, F);

    agg_bf16<<<(ND1 + 3) / 4, 256, 0, stream>>>(h, es1, off1, cnt + NS0 + ND0 + ND0, rsq_in1, agg1, ND1);

    gemm128<float><<<dim3((ND1 + 127) / 128, OF / 128), 256, 0, stream>>>(
        agg1, wt2, b2, nullptr, out, ND1, OF, F);
}

// Round 5
// 587.623 us; speedup vs baseline: 1.1780x; 1.0350x over previous
//
#include <hip/hip_runtime.h>

typedef unsigned short ushort_t;
typedef unsigned int uint_t;
typedef __attribute__((ext_vector_type(8))) short s8v;     // 8 x bf16 (4 VGPRs)
typedef __attribute__((ext_vector_type(4))) float f4v;     // 4 x fp32 acc (native vec, NT-load ok)

// Problem constants (fixed by the reference)
#define NS0 100000
#define ND0 20000
#define ND1 4000
#define E0  640000
#define E1  128000
#define F   512     // IN_F == HID_F
#define OF  256

__device__ __forceinline__ ushort_t f2b(float f) {
    uint_t u = __float_as_uint(f);
    uint_t r = (u + 0x7fffu + ((u >> 16) & 1u)) >> 16;
    return (ushort_t)r;
}
__device__ __forceinline__ float b2f_lo(uint_t u) { return __uint_as_float(u << 16); }
__device__ __forceinline__ float b2f_hi(uint_t u) { return __uint_as_float(u & 0xffff0000u); }

// ---- degree counting: cnt layout [out0(100000) | in0(20000) | out1(20000) | in1(4000)]
__global__ __launch_bounds__(256) void count_deg(const int* __restrict__ src0, const int* __restrict__ dst0,
                                                 const int* __restrict__ src1, const int* __restrict__ dst1,
                                                 int* __restrict__ cnt) {
    int i = blockIdx.x * 256 + threadIdx.x;
    int stride = gridDim.x * 256;
    for (int e = i; e < E0; e += stride) {
        atomicAdd(&cnt[src0[e]], 1);
        atomicAdd(&cnt[NS0 + dst0[e]], 1);
    }
    for (int e = i; e < E1; e += stride) {
        atomicAdd(&cnt[NS0 + ND0 + src1[e]], 1);
        atomicAdd(&cnt[NS0 + ND0 + ND0 + dst1[e]], 1);
    }
}

// Fused: block 0 scans level-0 CSR offsets, block 1 scans level-1, blocks >=2 compute rsq.
// Chunked scan: thread t serially owns ch contiguous elements; 2 barriers total.
__global__ __launch_bounds__(1024) void pre2(const int* __restrict__ cnt, float* __restrict__ rsq, int ncnt,
                                             int* __restrict__ off0, int* __restrict__ cur0,
                                             int* __restrict__ off1, int* __restrict__ cur1) {
    if (blockIdx.x >= 2) {
        int i = (blockIdx.x - 2) * 1024 + threadIdx.x;
        if (i < ncnt) rsq[i] = rsqrtf(fmaxf((float)cnt[i], 1.0f));
        return;
    }
    const int* c = blockIdx.x ? (cnt + NS0 + ND0 + ND0) : (cnt + NS0);
    int n = blockIdx.x ? ND1 : ND0;
    int* off = blockIdx.x ? off1 : off0;
    int* cur = blockIdx.x ? cur1 : cur0;
    __shared__ int wsum[16];
    __shared__ int wexc[16];
    int lid = threadIdx.x, lane = lid & 63, w = lid >> 6;
    int ch = (n + 1023) >> 10;
    int s0 = lid * ch;
    int e0 = min(s0 + ch, n);
    int sum = 0;
    for (int i = s0; i < e0; ++i) sum += c[i];
    int s = sum;
    #pragma unroll
    for (int d = 1; d < 64; d <<= 1) { int t = __shfl_up(s, d, 64); if (lane >= d) s += t; }
    if (lane == 63) wsum[w] = s;
    __syncthreads();
    if (w == 0 && lane < 16) {
        int ws = wsum[lane];
        int ss = ws;
        #pragma unroll
        for (int d = 1; d < 16; d <<= 1) { int t = __shfl_up(ss, d, 64); if (lane >= d) ss += t; }
        wexc[lane] = ss - ws;
    }
    __syncthreads();
    int run = wexc[w] + s - sum;   // global exclusive prefix at s0
    for (int i = s0; i < e0; ++i) {
        int v = c[i];
        off[i] = run; cur[i] = run;
        run += v;
    }
}

__global__ __launch_bounds__(256) void fill_edges(const int* __restrict__ src0, const int* __restrict__ dst0,
                                                  const int* __restrict__ src1, const int* __restrict__ dst1,
                                                  int* __restrict__ cur0, int* __restrict__ cur1,
                                                  int* __restrict__ es0, int* __restrict__ es1) {
    int i = blockIdx.x * 256 + threadIdx.x;
    int stride = gridDim.x * 256;
    for (int e = i; e < E0; e += stride) {
        int d = dst0[e];
        int p = atomicAdd(&cur0[d], 1);
        es0[p] = src0[e];
    }
    for (int e = i; e < E1; e += stride) {
        int d = dst1[e];
        int p = atomicAdd(&cur1[d], 1);
        es1[p] = src1[e];
    }
}

// Fused weight-transpose-convert (blocks [0,1536)) + x convert (blocks >= 1536).
// x reads are NON-TEMPORAL: the 205 MB fp32 stream must not evict xb from L3 —
// the L1 gather re-reads xb ~6.4x and needs it L3-resident (R1: 313MB fetch vs 102MB working set).
#define WBLK ((F * F + F * OF) / 256)      // 1536
__global__ __launch_bounds__(256) void conv_wx(const float* __restrict__ W1, const float* __restrict__ W2,
                                               ushort_t* __restrict__ wt1, ushort_t* __restrict__ wt2,
                                               const float* __restrict__ x, const float* __restrict__ rsq_out0,
                                               ushort_t* __restrict__ xb) {
    if (blockIdx.x < WBLK) {
        int i = blockIdx.x * 256 + threadIdx.x;
        if (i < F * F) {
            int k = i >> 9, n = i & (F - 1);
            wt1[n * F + k] = f2b(W1[i]);
        } else {
            int j = i - F * F;
            int k = j >> 8, n = j & (OF - 1);
            wt2[n * F + k] = f2b(W2[j]);
        }
        return;
    }
    int i = (blockIdx.x - WBLK) * 256 + threadIdx.x;   // quad index; 128 quads per row
    if (i >= NS0 * 128) return;
    int row = i >> 7;
    f4v v = __builtin_nontemporal_load(((const f4v*)x) + i);
    float sc = rsq_out0[row];
    uint2 o;
    o.x = (uint_t)f2b(v.x * sc) | ((uint_t)f2b(v.y * sc) << 16);
    o.y = (uint_t)f2b(v.z * sc) | ((uint_t)f2b(v.w * sc) << 16);
    ((uint2*)xb)[i] = o;
}

__device__ __forceinline__ void add8(float* acc, uint4 u) {
    acc[0] += b2f_lo(u.x); acc[1] += b2f_hi(u.x);
    acc[2] += b2f_lo(u.y); acc[3] += b2f_hi(u.y);
    acc[4] += b2f_lo(u.z); acc[5] += b2f_hi(u.z);
    acc[6] += b2f_lo(u.w); acc[7] += b2f_hi(u.w);
}

// One wave per dst row. 64 lanes x 16B = full 1024B row per load instruction.
// Edge loop unrolled x16 -> 16 independent gathers in flight per wave (avg degree 32).
__global__ __launch_bounds__(256) void agg_bf16(const ushort_t* __restrict__ X, const int* __restrict__ es,
                                                const int* __restrict__ off, const int* __restrict__ cnt,
                                                const float* __restrict__ rsq_in, ushort_t* __restrict__ out,
                                                int ndst) {
    int d = __builtin_amdgcn_readfirstlane(blockIdx.x * 4 + (threadIdx.x >> 6));
    if (d >= ndst) return;
    int lane = threadIdx.x & 63;
    int base = off[d], n = cnt[d];
    const uint4* Xv = (const uint4*)X;
    float acc[8] = {0.f, 0.f, 0.f, 0.f, 0.f, 0.f, 0.f, 0.f};
    int i = 0;
    for (; i + 16 <= n; i += 16) {
        uint4 u[16];
        #pragma unroll
        for (int j = 0; j < 16; ++j) u[j] = Xv[(size_t)es[base + i + j] * 64 + lane];
        #pragma unroll
        for (int j = 0; j < 16; ++j) add8(acc, u[j]);
    }
    for (; i + 4 <= n; i += 4) {
        uint4 u[4];
        #pragma unroll
        for (int j = 0; j < 4; ++j) u[j] = Xv[(size_t)es[base + i + j] * 64 + lane];
        #pragma unroll
        for (int j = 0; j < 4; ++j) add8(acc, u[j]);
    }
    for (; i < n; ++i) add8(acc, Xv[(size_t)es[base + i] * 64 + lane]);
    float sc = rsq_in[d];
    uint4 o;
    o.x = (uint_t)f2b(acc[0] * sc) | ((uint_t)f2b(acc[1] * sc) << 16);
    o.y = (uint_t)f2b(acc[2] * sc) | ((uint_t)f2b(acc[3] * sc) << 16);
    o.z = (uint_t)f2b(acc[4] * sc) | ((uint_t)f2b(acc[5] * sc) << 16);
    o.w = (uint_t)f2b(acc[6] * sc) | ((uint_t)f2b(acc[7] * sc) << 16);
    ((uint4*)out)[(size_t)d * 64 + lane] = o;
}

// fallback when ws too small for xb: gather fp32 x, scale by rsq_out0[src]
__global__ __launch_bounds__(256) void agg_f32(const float* __restrict__ X, const float* __restrict__ rsq_out,
                                               const int* __restrict__ es, const int* __restrict__ off,
                                               const int* __restrict__ cnt, const float* __restrict__ rsq_in,
                                               ushort_t* __restrict__ out) {
    int d = blockIdx.x;
    int t = threadIdx.x;
    int base = off[d], n = cnt[d];
    float ax = 0.f, ay = 0.f;
    for (int i = 0; i < n; ++i) {
        int s = es[base + i];
        float2 v = ((const float2*)X)[(size_t)s * 256 + t];
        float sc = rsq_out[s];
        ax += v.x * sc;
        ay += v.y * sc;
    }
    float sc = rsq_in[d];
    ax *= sc; ay *= sc;
    ((uint_t*)out)[(size_t)d * 256 + t] = (uint_t)f2b(ax) | ((uint_t)f2b(ay) << 16);
}

// m97-style GEMM: C[M,N] = relu(A[M,K]bf16 @ BT[N,K]bf16^T + bias) (* rowScale)
// 128x128 tile / 256 threads / BK=64; global_load_lds 16B staging; 32 MFMA per K-step/wave.
template <typename OutT>
__global__ __launch_bounds__(256) void gemm128(const ushort_t* __restrict__ A, const ushort_t* __restrict__ BT,
                                               const float* __restrict__ bias, const float* __restrict__ rowScale,
                                               OutT* __restrict__ C, int M, int N, int K) {
    __shared__ __align__(16) ushort_t As[128 * 64];
    __shared__ __align__(16) ushort_t Bs[128 * 64];
    int tid = threadIdx.x;
    int lane = tid & 63, w = tid >> 6;
    int m16 = lane & 15, quad = lane >> 4;
    int wm = w & 1, wn = w >> 1;
    int bm = blockIdx.x * 128, bn = blockIdx.y * 128;
    f4v acc[4][4] = {};
    for (int k0 = 0; k0 < K; k0 += 64) {
        #pragma unroll
        for (int i = 0; i < 4; ++i) {
            int c = i * 256 + tid;          // chunk id: row = c>>3, 16B seg = c&7
            int row = c >> 3, seg = (c & 7) * 8;
            int ra = bm + row; if (ra >= M) ra = M - 1;
            __builtin_amdgcn_global_load_lds(
                (const __attribute__((address_space(1))) uint_t*)(A + (size_t)ra * K + k0 + seg),
                (__attribute__((address_space(3))) uint_t*)(As + (size_t)c * 8), 16, 0, 0);
        }
        #pragma unroll
        for (int i = 0; i < 4; ++i) {
            int c = i * 256 + tid;
            int row = c >> 3, seg = (c & 7) * 8;
            int rb = bn + row;              // N is a multiple of 128 here
            __builtin_amdgcn_global_load_lds(
                (const __attribute__((address_space(1))) uint_t*)(BT + (size_t)rb * K + k0 + seg),
                (__attribute__((address_space(3))) uint_t*)(Bs + (size_t)c * 8), 16, 0, 0);
        }
        __syncthreads();
        #pragma unroll
        for (int kc = 0; kc < 2; ++kc) {
            int co = kc * 32 + quad * 8;
            s8v af[4], bf[4];
            #pragma unroll
            for (int m = 0; m < 4; ++m)
                af[m] = *(const s8v*)&As[(wm * 64 + m * 16 + m16) * 64 + co];
            #pragma unroll
            for (int nn = 0; nn < 4; ++nn)
                bf[nn] = *(const s8v*)&Bs[(wn * 64 + nn * 16 + m16) * 64 + co];
            #pragma unroll
            for (int m = 0; m < 4; ++m)
                #pragma unroll
                for (int nn = 0; nn < 4; ++nn)
                    acc[m][nn] = __builtin_amdgcn_mfma_f32_16x16x32_bf16(af[m], bf[nn], acc[m][nn], 0, 0, 0);
        }
        __syncthreads();
    }
    #pragma unroll
    for (int m = 0; m < 4; ++m) {
        #pragma unroll
        for (int rr = 0; rr < 4; ++rr) {
            int row = bm + wm * 64 + m * 16 + quad * 4 + rr;
            if (row < M) {
                float rs = rowScale ? rowScale[row] : 1.0f;
                #pragma unroll
                for (int nn = 0; nn < 4; ++nn) {
                    int col = bn + wn * 64 + nn * 16 + m16;
                    float v = fmaxf(acc[m][nn][rr] + bias[col], 0.0f) * rs;
                    if (sizeof(OutT) == 2)
                        ((ushort_t*)C)[(size_t)row * N + col] = f2b(v);
                    else
                        ((float*)C)[(size_t)row * N + col] = v;
                }
            }
        }
    }
}

extern "C" void kernel_launch(void* const* d_in, const int* in_sizes, int n_in,
                              void* d_out, int out_size, void* d_ws, size_t ws_size,
                              hipStream_t stream) {
    (void)in_sizes; (void)n_in; (void)out_size;
    const float* x    = (const float*)d_in[0];
    const int*   src0 = (const int*)d_in[1];
    const int*   dst0 = (const int*)d_in[2];
    const int*   src1 = (const int*)d_in[3];
    const int*   dst1 = (const int*)d_in[4];
    const float* W1   = (const float*)d_in[5];
    const float* b1   = (const float*)d_in[6];
    const float* W2   = (const float*)d_in[7];
    const float* b2   = (const float*)d_in[8];
    float* out = (float*)d_out;

    char* p = (char*)d_ws;
    auto alloc = [&](size_t bytes) { char* q = p; p += (bytes + 255) & ~(size_t)255; return q; };
    const int NCNT = NS0 + ND0 + ND0 + ND1;      // 144000
    int*      cnt  = (int*)alloc((size_t)NCNT * 4);
    float*    rsq  = (float*)alloc((size_t)NCNT * 4);
    int*      off0 = (int*)alloc((size_t)ND0 * 4);
    int*      cur0 = (int*)alloc((size_t)ND0 * 4);
    int*      off1 = (int*)alloc((size_t)ND1 * 4);
    int*      cur1 = (int*)alloc((size_t)ND1 * 4);
    int*      es0  = (int*)alloc((size_t)E0 * 4);
    int*      es1  = (int*)alloc((size_t)E1 * 4);
    ushort_t* wt1  = (ushort_t*)alloc((size_t)F * F * 2);
    ushort_t* wt2  = (ushort_t*)alloc((size_t)OF * F * 2);
    ushort_t* agg0 = (ushort_t*)alloc((size_t)ND0 * F * 2);
    ushort_t* h    = (ushort_t*)alloc((size_t)ND0 * F * 2);
    ushort_t* agg1 = (ushort_t*)alloc((size_t)ND1 * F * 2);
    size_t used = (size_t)(p - (char*)d_ws);
    bool use_xb = (ws_size >= used + (size_t)NS0 * F * 2 + 512);
    ushort_t* xb = use_xb ? (ushort_t*)alloc((size_t)NS0 * F * 2) : nullptr;

    const float* rsq_out0 = rsq;
    const float* rsq_in0  = rsq + NS0;
    const float* rsq_out1 = rsq + NS0 + ND0;
    const float* rsq_in1  = rsq + NS0 + ND0 + ND0;

    (void)hipMemsetAsync(cnt, 0, (size_t)NCNT * 4, stream);
    count_deg<<<E0 / 256, 256, 0, stream>>>(src0, dst0, src1, dst1, cnt);
    pre2<<<2 + (NCNT + 1023) / 1024, 1024, 0, stream>>>(cnt, rsq, NCNT, off0, cur0, off1, cur1);
    fill_edges<<<E0 / 256, 256, 0, stream>>>(src0, dst0, src1, dst1, cur0, cur1, es0, es1);

    if (use_xb) {
        conv_wx<<<WBLK + (NS0 * 128 + 255) / 256, 256, 0, stream>>>(W1, W2, wt1, wt2, x, rsq_out0, xb);
        agg_bf16<<<(ND0 + 3) / 4, 256, 0, stream>>>(xb, es0, off0, cnt + NS0, rsq_in0, agg0, ND0);
    } else {
        conv_wx<<<WBLK, 256, 0, stream>>>(W1, W2, wt1, wt2, x, rsq_out0, nullptr);
        agg_f32<<<ND0, 256, 0, stream>>>(x, rsq_out0, es0, off0, cnt + NS0, rsq_in0, agg0);
    }

    gemm128<ushort_t><<<dim3((ND0 + 127) / 128, F / 128), 256, 0, stream>>>(
        agg0, wt1, b1, rsq_out1, h, ND0, F, F);

    agg_bf16<<<(ND1 + 3) / 4, 256, 0, stream>>>(h, es1, off1, cnt + NS0 + ND0 + ND0, rsq_in1, agg1, ND1);

    gemm128<float><<<dim3((ND1 + 127) / 128, OF / 128), 256, 0, stream>>>(
        agg1, wt2, b2, nullptr, out, ND1, OF, F);
}